// Round 2
// baseline (617.202 us; speedup 1.0000x reference)
//
#include <hip/hip_runtime.h>

static constexpr int Wd  = 128;
static constexpr int Hd  = 128;
static constexpr int HWc = Wd * Hd;    // 16384
static constexpr int Cc  = 128;
static constexpr int NHc = 4;
static constexpr int Bc  = 2;

__device__ __forceinline__ int refl(int i, int L) {
    i = i < 0 ? -i : i;
    return i >= L ? 2 * (L - 1) - i : i;
}

// ---------------- Kernel A: depthwise 3x3 + bias + relu (zero padding) ----------------
__global__ __launch_bounds__(256) void dw_kernel(
    const float* __restrict__ vid,
    const float* __restrict__ wq, const float* __restrict__ bq,
    const float* __restrict__ wk, const float* __restrict__ bk,
    const float* __restrict__ wv, const float* __restrict__ bv,
    float* __restrict__ yq, float* __restrict__ yk, float* __restrict__ yv)
{
    int pix  = blockIdx.x * 256 + threadIdx.x;
    int bc   = blockIdx.y;           // b*C + c
    int conv = blockIdx.z;
    const float* wsel = conv == 0 ? wq : (conv == 1 ? wk : wv);
    const float* bsel = conv == 0 ? bq : (conv == 1 ? bk : bv);
    float* osel       = conv == 0 ? yq : (conv == 1 ? yk : yv);
    int c = bc & (Cc - 1);
    int y = pix >> 7, x = pix & (Wd - 1);
    const float* src = vid + (size_t)bc * HWc;
    const float* wp  = wsel + c * 9;
    float acc = 0.f;
    #pragma unroll
    for (int ky = 0; ky < 3; ++ky) {
        int iy = y + ky - 1;
        if (iy < 0 || iy >= Hd) continue;
        #pragma unroll
        for (int kx = 0; kx < 3; ++kx) {
            int ix = x + kx - 1;
            if (ix < 0 || ix >= Wd) continue;
            acc = fmaf(src[iy * Wd + ix], wp[ky * 3 + kx], acc);
        }
    }
    acc += bsel[c];
    osel[(size_t)bc * HWc + pix] = fmaxf(acc, 0.f);
}

// ---------------- Kernel B/D: pointwise GEMM, c-major in/out, in-place safe ----------
// out[o,p] = (sum_c w[o,c]*y[c,p] + b[o]) * scale.  In and out may alias (same layout,
// each block reads and writes exactly its own 128-pixel range, all reads before writes).
__global__ __launch_bounds__(256) void pw_kernel(
    const float* y0p, const float* y1p, const float* y2p,
    const float* __restrict__ w0,  const float* __restrict__ w1,  const float* __restrict__ w2,
    const float* __restrict__ b0,  const float* __restrict__ b1,  const float* __restrict__ b2,
    float* o0, float* o1, float* o2,
    float scale0)
{
    extern __shared__ float lds[];
    float* wl = lds;            // [64 cc][129]  wl[cc*129 + o]  (conflict-free both ways)
    float* yl = lds + 8256;     // [64 cc][128 p]

    int z = blockIdx.z;
    const float* yin  = z == 0 ? y0p : (z == 1 ? y1p : y2p);
    const float* wmat = z == 0 ? w0  : (z == 1 ? w1  : w2);
    const float* bias = z == 0 ? b0  : (z == 1 ? b1  : b2);
    float* out        = z == 0 ? o0  : (z == 1 ? o1  : o2);
    float scale       = z == 0 ? scale0 : 1.f;

    int tid = threadIdx.x;
    int ot = tid & 15, pt = tid >> 4;
    int gp  = blockIdx.x * 128;
    int b   = gp >> 14;
    int pof = gp & (HWc - 1);
    const float* yb = yin + (size_t)b * Cc * HWc + pof;

    float acc[8][8];
    #pragma unroll
    for (int i = 0; i < 8; ++i)
        #pragma unroll
        for (int j = 0; j < 8; ++j) acc[i][j] = 0.f;

    for (int kh = 0; kh < 2; ++kh) {
        int c0 = kh * 64;
        // stage weights: 64 c x 128 o. lanes vary cc -> global 64-contig, LDS bank-clean
        for (int i = tid; i < 8192; i += 256) {
            int cc = i & 63, o = i >> 6;
            wl[cc * 129 + o] = wmat[o * 128 + c0 + cc];
        }
        // stage y tile: 64 c x 128 p (coalesced, bank-clean)
        for (int i = tid; i < 8192; i += 256) {
            int p = i & 127, cc = i >> 7;
            yl[cc * 128 + p] = yb[(size_t)(c0 + cc) * HWc + p];
        }
        __syncthreads();
        #pragma unroll 4
        for (int cc = 0; cc < 64; ++cc) {
            float wv[8], pv[8];
            #pragma unroll
            for (int oi = 0; oi < 8; ++oi) wv[oi] = wl[cc * 129 + oi * 16 + ot];
            #pragma unroll
            for (int pi = 0; pi < 8; ++pi) pv[pi] = yl[cc * 128 + pi * 16 + pt];
            #pragma unroll
            for (int oi = 0; oi < 8; ++oi)
                #pragma unroll
                for (int pi = 0; pi < 8; ++pi)
                    acc[oi][pi] = fmaf(wv[oi], pv[pi], acc[oi][pi]);
        }
        __syncthreads();
    }

    float bia[8];
    #pragma unroll
    for (int oi = 0; oi < 8; ++oi) bia[oi] = bias[oi * 16 + ot];

    // epilogue staging: lds[p*133 + o] — writes conflict-free (ot-lanes contiguous),
    // reads (5p+o)%32 covers all banks, stores coalesced 128-contig.
    #pragma unroll
    for (int oi = 0; oi < 8; ++oi)
        #pragma unroll
        for (int pi = 0; pi < 8; ++pi)
            lds[(pi * 16 + pt) * 133 + oi * 16 + ot] = (acc[oi][pi] + bia[oi]) * scale;
    __syncthreads();

    for (int i = tid; i < 16384; i += 256) {
        int p = i & 127, o = i >> 7;
        out[(size_t)b * Cc * HWc + (size_t)o * HWc + pof + p] = lds[p * 133 + o];
    }
}

// ---------------- Kernel C: neighborhood attention (top-16 of 8x8 window) -------------
// q,k,v all c-major (B,C,H,W). att written in-place over q (tile-local q reads).
__global__ __launch_bounds__(256) void attn_kernel(
    const float* q, const float* kk, const float* vv, float* att)
{
    extern __shared__ float lds[];   // 529 region pixels * 36 floats (144B stride)
    int tid = threadIdx.x;
    int tx = tid & 15, ty = tid >> 4;
    int x0 = blockIdx.x * 16, y0 = blockIdx.y * 16;
    int bn = blockIdx.z;             // b*NH + n  (channel base bn*32)
    const float* kb = kk + (size_t)bn * 32 * HWc;
    const float* vb = vv + (size_t)bn * 32 * HWc;

    // q into registers (tile-local)
    float qv[32];
    {
        const float* qp = q + (size_t)bn * 32 * HWc + (y0 + ty) * Wd + (x0 + tx);
        #pragma unroll
        for (int c = 0; c < 32; ++c) qv[c] = qp[(size_t)c * HWc];
    }

    // stage K region (23x23 pixels, 32 ch, reflect): c-major source, pix-fastest loop
    for (int u = tid; u < 529 * 32; u += 256) {
        int c = u / 529, pix = u - c * 529;
        int ry = pix / 23, rx = pix - ry * 23;
        int gy = refl(y0 - 4 + ry, Hd);
        int gx = refl(x0 - 4 + rx, Wd);
        lds[pix * 36 + c] = kb[(size_t)c * HWc + gy * Wd + gx];
    }
    __syncthreads();

    // QK: 64 dists (float4 LDS reads, 144B pixel stride -> conflict-free)
    float d[64];
    #pragma unroll
    for (int i = 0; i < 64; ++i) d[i] = 0.f;
    int pbase = ty * 23 + tx;
    #pragma unroll
    for (int cb = 0; cb < 8; ++cb) {
        float4 q4 = make_float4(qv[cb*4], qv[cb*4+1], qv[cb*4+2], qv[cb*4+3]);
        #pragma unroll
        for (int off = 0; off < 64; ++off) {
            int dy = off >> 3, dx = off & 7;
            const float4 kv = *(const float4*)(lds + (pbase + dy * 23 + dx) * 36 + cb * 4);
            d[off] = fmaf(q4.x, kv.x, fmaf(q4.y, kv.y, fmaf(q4.z, kv.z, fmaf(q4.w, kv.w, d[off]))));
        }
    }
    __syncthreads();

    // stage V region (overwrite LDS)
    for (int u = tid; u < 529 * 32; u += 256) {
        int c = u / 529, pix = u - c * 529;
        int ry = pix / 23, rx = pix - ry * 23;
        int gy = refl(y0 - 4 + ry, Hd);
        int gx = refl(x0 - 4 + rx, Wd);
        lds[pix * 36 + c] = vb[(size_t)c * HWc + gy * Wd + gx];
    }

    // pairwise ranking, packed 4 ranks/u32 (saves 48 VGPRs vs int rk[64]).
    // lower index wins ties == lax.top_k semantics.
    unsigned rk[16];
    #pragma unroll
    for (int i = 0; i < 16; ++i) rk[i] = 0u;
    #pragma unroll
    for (int i = 0; i < 63; ++i) {
        #pragma unroll
        for (int j = i + 1; j < 64; ++j) {
            bool ge = d[i] >= d[j];
            rk[i >> 2] += ge ? 0u : (1u << (8 * (i & 3)));
            rk[j >> 2] += ge ? (1u << (8 * (j & 3))) : 0u;
        }
    }
    float m = d[0];
    #pragma unroll
    for (int i = 1; i < 64; ++i) m = fmaxf(m, d[i]);
    float s = 0.f;
    #pragma unroll
    for (int i = 0; i < 64; ++i) {
        unsigned r = (rk[i >> 2] >> (8 * (i & 3))) & 255u;
        float e = (r < 16u) ? __expf(d[i] - m) : 0.f;
        d[i] = e;
        s += e;
    }
    float inv = 1.0f / s;
    __syncthreads();

    // PV: weighted gather from V (weights zero for unselected offsets)
    float acc[32];
    #pragma unroll
    for (int c = 0; c < 32; ++c) acc[c] = 0.f;
    #pragma unroll
    for (int cb = 0; cb < 8; ++cb) {
        #pragma unroll
        for (int off = 0; off < 64; ++off) {
            int dy = off >> 3, dx = off & 7;
            const float4 vv4 = *(const float4*)(lds + (pbase + dy * 23 + dx) * 36 + cb * 4);
            float wg = d[off];
            acc[cb*4+0] = fmaf(wg, vv4.x, acc[cb*4+0]);
            acc[cb*4+1] = fmaf(wg, vv4.y, acc[cb*4+1]);
            acc[cb*4+2] = fmaf(wg, vv4.z, acc[cb*4+2]);
            acc[cb*4+3] = fmaf(wg, vv4.w, acc[cb*4+3]);
        }
    }

    float* op = att + (size_t)bn * 32 * HWc + (y0 + ty) * Wd + (x0 + tx);
    #pragma unroll
    for (int c = 0; c < 32; ++c) op[(size_t)c * HWc] = acc[c] * inv;
}

// ---------------------------------- launcher ------------------------------------------
extern "C" void kernel_launch(void* const* d_in, const int* in_sizes, int n_in,
                              void* d_out, int out_size, void* d_ws, size_t ws_size,
                              hipStream_t stream)
{
    const float* vid  = (const float*)d_in[0];
    const float* qdww = (const float*)d_in[1];
    const float* qdwb = (const float*)d_in[2];
    const float* qpww = (const float*)d_in[3];
    const float* qpwb = (const float*)d_in[4];
    const float* kdww = (const float*)d_in[5];
    const float* kdwb = (const float*)d_in[6];
    const float* kpww = (const float*)d_in[7];
    const float* kpwb = (const float*)d_in[8];
    const float* vdww = (const float*)d_in[9];
    const float* vdwb = (const float*)d_in[10];
    const float* vpww = (const float*)d_in[11];
    const float* vpwb = (const float*)d_in[12];
    const float* pjw  = (const float*)d_in[13];
    const float* pjb  = (const float*)d_in[14];

    float* ws = (float*)d_ws;
    const size_t SZ = (size_t)Bc * Cc * HWc;   // 4,194,304 floats (16 MB)
    float* buf0 = ws;            // q-dw -> q -> att   (in-place chain)
    float* buf1 = ws + SZ;       // k-dw -> k
    float* buf2 = ws + 2 * SZ;   // v-dw -> v
    // total ws use: 48 MB

    hipFuncSetAttribute((const void*)pw_kernel,   hipFuncAttributeMaxDynamicSharedMemorySize, 68096);
    hipFuncSetAttribute((const void*)attn_kernel, hipFuncAttributeMaxDynamicSharedMemorySize, 76176);

    // depthwise (all three branches)
    dw_kernel<<<dim3(HWc / 256, Bc * Cc, 3), 256, 0, stream>>>(
        vid, qdww, qdwb, kdww, kdwb, vdww, vdwb, buf0, buf1, buf2);

    // pointwise q/k/v, all in-place c-major (q scaled by HD^-1/2)
    const float scale = 0.17677669529663687f;
    pw_kernel<<<dim3((Bc * HWc) / 128, 1, 3), 256, 68096, stream>>>(
        buf0, buf1, buf2, qpww, kpww, vpww, qpwb, kpwb, vpwb, buf0, buf1, buf2, scale);

    // neighborhood attention: att in-place over q
    attn_kernel<<<dim3(Wd / 16, Hd / 16, Bc * NHc), 256, 76176, stream>>>(buf0, buf1, buf2, buf0);

    // projection -> d_out (B,C,H,W)
    pw_kernel<<<dim3((Bc * HWc) / 128, 1, 1), 256, 68096, stream>>>(
        buf0, buf0, buf0, pjw, pjw, pjw, pjb, pjb, pjb, (float*)d_out, (float*)d_out, (float*)d_out, 1.f);
}